// Round 1
// baseline (215.253 us; speedup 1.0000x reference)
//
#include <hip/hip_runtime.h>

// QuantizedWeight dequant:
//   out[o, i*8+j] = (cb[0, codes[o,i,0], 0, j] + cb[1, codes[o,i,1], 0, j]) * scales[o,i] + zeros[o,i]
// Shapes: codes (8192,1024,2) i32, codebooks (2,65536,1,8) f32,
//         scales/zeros (8192,1024,1,1) f32, out (8192,8192) f32.
// Flat output offset for group idx = o*1024+i is simply idx*8.

__global__ __launch_bounds__(256) void
dequant_kernel(const int* __restrict__ codes,
               const float* __restrict__ codebooks,   // [2][65536][8]
               const float* __restrict__ scales,
               const float* __restrict__ zeros,
               float* __restrict__ out,
               int total)                              // = 8192*1024 groups
{
    const size_t CB1_OFF = (size_t)65536 * 8;          // second codebook base (floats)

    for (int idx = blockIdx.x * blockDim.x + threadIdx.x;
         idx < total;
         idx += gridDim.x * blockDim.x)
    {
        // two codes for this group, contiguous
        int2 c = *reinterpret_cast<const int2*>(codes + (size_t)2 * idx);
        float s = scales[idx];
        float z = zeros[idx];

        const float4* e0 = reinterpret_cast<const float4*>(codebooks + (size_t)c.x * 8);
        const float4* e1 = reinterpret_cast<const float4*>(codebooks + CB1_OFF + (size_t)c.y * 8);

        float4 a0 = e0[0], a1 = e0[1];
        float4 b0 = e1[0], b1 = e1[1];

        float4 r0, r1;
        r0.x = (a0.x + b0.x) * s + z;
        r0.y = (a0.y + b0.y) * s + z;
        r0.z = (a0.z + b0.z) * s + z;
        r0.w = (a0.w + b0.w) * s + z;
        r1.x = (a1.x + b1.x) * s + z;
        r1.y = (a1.y + b1.y) * s + z;
        r1.z = (a1.z + b1.z) * s + z;
        r1.w = (a1.w + b1.w) * s + z;

        float4* o4 = reinterpret_cast<float4*>(out + (size_t)idx * 8);
        o4[0] = r0;
        o4[1] = r1;
    }
}

extern "C" void kernel_launch(void* const* d_in, const int* in_sizes, int n_in,
                              void* d_out, int out_size, void* d_ws, size_t ws_size,
                              hipStream_t stream) {
    const int*   codes     = (const int*)  d_in[0];
    const float* codebooks = (const float*)d_in[1];
    const float* scales    = (const float*)d_in[2];
    const float* zeros     = (const float*)d_in[3];
    float*       out       = (float*)d_out;

    const int total = in_sizes[0] / 2;   // number of (o,i) groups = 8192*1024

    const int threads = 256;
    int blocks = (total + threads - 1) / threads;
    if (blocks > 2048) blocks = 2048;    // grid-stride, ~8 blocks/CU

    dequant_kernel<<<blocks, threads, 0, stream>>>(
        codes, codebooks, scales, zeros, out, total);
}

// Round 2
// 201.430 us; speedup vs baseline: 1.0686x; 1.0686x over previous
//
#include <hip/hip_runtime.h>

// QuantizedWeight dequant:
//   out[o, i*8+j] = (cb[0, codes[o,i,0], 0, j] + cb[1, codes[o,i,1], 0, j]) * scales[o,i] + zeros[o,i]
// codes (8192,1024,2) i32, codebooks (2,65536,1,8) f32, scales/zeros (8192,1024) f32,
// out (8192,8192) f32. Output flat offset for group idx = idx*8.
//
// Strategy: streaming traffic (codes/scales/zeros/out) uses nontemporal ops so
// the 4 MB codebook stays resident in each XCD's 4 MiB L2; gathers use cached
// loads. 2x unroll batches 8 independent 16B gathers per thread for MLP.

typedef float vf4 __attribute__((ext_vector_type(4)));
typedef int   vi2 __attribute__((ext_vector_type(2)));

__global__ __launch_bounds__(256) void
dequant_kernel(const int* __restrict__ codes,
               const float* __restrict__ cbs,      // [2][65536][8]
               const float* __restrict__ scales,
               const float* __restrict__ zeros,
               float* __restrict__ out,
               int total)                           // 8192*1024 groups
{
    const size_t CB1 = (size_t)65536 * 8;           // second codebook base (floats)
    const int stride = gridDim.x * blockDim.x;
    int idx = blockIdx.x * blockDim.x + threadIdx.x;

    // main loop: 2 groups per iteration (independent gathers batched)
    for (; idx + stride < total; idx += 2 * stride) {
        const int j0 = idx;
        const int j1 = idx + stride;

        // streaming reads (nt: don't pollute L2)
        vi2 c0 = __builtin_nontemporal_load(((const vi2*)codes) + j0);
        vi2 c1 = __builtin_nontemporal_load(((const vi2*)codes) + j1);
        float s0 = __builtin_nontemporal_load(scales + j0);
        float s1 = __builtin_nontemporal_load(scales + j1);
        float z0 = __builtin_nontemporal_load(zeros + j0);
        float z1 = __builtin_nontemporal_load(zeros + j1);

        // 8 independent gathers (cached — codebook should L2-hit)
        const vf4* e00 = (const vf4*)(cbs + (size_t)c0.x * 8);
        const vf4* e01 = (const vf4*)(cbs + CB1 + (size_t)c0.y * 8);
        const vf4* e10 = (const vf4*)(cbs + (size_t)c1.x * 8);
        const vf4* e11 = (const vf4*)(cbs + CB1 + (size_t)c1.y * 8);

        vf4 a0 = e00[0], a1 = e00[1];
        vf4 b0 = e01[0], b1 = e01[1];
        vf4 a2 = e10[0], a3 = e10[1];
        vf4 b2 = e11[0], b3 = e11[1];

        vf4 r0 = (a0 + b0) * s0 + z0;
        vf4 r1 = (a1 + b1) * s0 + z0;
        vf4 r2 = (a2 + b2) * s1 + z1;
        vf4 r3 = (a3 + b3) * s1 + z1;

        // streaming writes (nt: never re-read)
        __builtin_nontemporal_store(r0, ((vf4*)out) + (size_t)2 * j0);
        __builtin_nontemporal_store(r1, ((vf4*)out) + (size_t)2 * j0 + 1);
        __builtin_nontemporal_store(r2, ((vf4*)out) + (size_t)2 * j1);
        __builtin_nontemporal_store(r3, ((vf4*)out) + (size_t)2 * j1 + 1);
    }

    // tail (single group)
    for (; idx < total; idx += stride) {
        vi2 c = __builtin_nontemporal_load(((const vi2*)codes) + idx);
        float s = __builtin_nontemporal_load(scales + idx);
        float z = __builtin_nontemporal_load(zeros + idx);
        const vf4* e0 = (const vf4*)(cbs + (size_t)c.x * 8);
        const vf4* e1 = (const vf4*)(cbs + CB1 + (size_t)c.y * 8);
        vf4 a0 = e0[0], a1 = e0[1];
        vf4 b0 = e1[0], b1 = e1[1];
        vf4 r0 = (a0 + b0) * s + z;
        vf4 r1 = (a1 + b1) * s + z;
        __builtin_nontemporal_store(r0, ((vf4*)out) + (size_t)2 * idx);
        __builtin_nontemporal_store(r1, ((vf4*)out) + (size_t)2 * idx + 1);
    }
}

extern "C" void kernel_launch(void* const* d_in, const int* in_sizes, int n_in,
                              void* d_out, int out_size, void* d_ws, size_t ws_size,
                              hipStream_t stream) {
    const int*   codes     = (const int*)  d_in[0];
    const float* codebooks = (const float*)d_in[1];
    const float* scales    = (const float*)d_in[2];
    const float* zeros     = (const float*)d_in[3];
    float*       out       = (float*)d_out;

    const int total = in_sizes[0] / 2;   // number of (o,i) groups

    const int threads = 256;
    int blocks = (total + threads - 1) / threads;
    if (blocks > 2048) blocks = 2048;    // grid-stride; 2048*4 waves = full residency

    dequant_kernel<<<blocks, threads, 0, stream>>>(
        codes, codebooks, scales, zeros, out, total);
}